// Round 2
// baseline (834.705 us; speedup 1.0000x reference)
//
#include <hip/hip_runtime.h>
#include <hip/hip_bf16.h>
#include <cstdint>

#define KDIM 32
#define RMAX 8

__device__ __forceinline__ float sigmoidf_(float x) {
    return 1.0f / (1.0f + expf(-x));
}

__device__ __forceinline__ float gate_weight_(float logit, float log_alpha) {
    // hard-concrete eval gate: pre = clip(la/temp, -2, 2); z = sig(pre)*1.2-0.1; clip[0,1]
    float pre = log_alpha * 1.5f;                 // / (2/3)
    pre = fminf(fmaxf(pre, -2.0f), 2.0f);
    float z = sigmoidf_(pre) * 1.2f - 0.1f;
    z = fminf(fmaxf(z, 0.0f), 1.0f);
    return sigmoidf_(logit) * z;
}

// ---- kernel 1: compute fused weights W[r][i][j]; also zero the histogram ----
__global__ void weights_kernel(const float* __restrict__ logits,
                               const float* __restrict__ la,
                               float* __restrict__ W, int n,
                               int* __restrict__ cnt, int R) {
    int g = blockIdx.x * blockDim.x + threadIdx.x;
    if (g < n) {
        W[g] = gate_weight_(logits[g], la[g]);
    }
    if (g < R) cnt[g] = 0;
}

// ---- kernel 2: histogram of edge_type ----
__global__ void hist_kernel(const int* __restrict__ et, int E,
                            int* __restrict__ cnt, int R) {
    __shared__ int h[RMAX];
    if ((int)threadIdx.x < R) h[threadIdx.x] = 0;
    __syncthreads();
    for (int i = blockIdx.x * blockDim.x + threadIdx.x; i < E;
         i += gridDim.x * blockDim.x) {
        atomicAdd(&h[et[i]], 1);
    }
    __syncthreads();
    if ((int)threadIdx.x < R) atomicAdd(&cnt[threadIdx.x], h[threadIdx.x]);
}

// ---- kernel 3: padded (64-aligned) bucket offsets + scatter cursors ----
__global__ void offsets_kernel(const int* __restrict__ cnt, int* __restrict__ off,
                               int* __restrict__ cur, int R) {
    if (threadIdx.x == 0 && blockIdx.x == 0) {
        int o = 0;
        off[0] = 0;
        for (int r = 0; r < R; r++) {
            cur[r] = o;
            o += (cnt[r] + 63) & ~63;
            off[r + 1] = o;
        }
    }
}

// ---- kernel 4: scatter edge ids into relation buckets (wave-aggregated atomics) ----
__global__ void scatter_kernel(const int* __restrict__ et, int E,
                               int* __restrict__ cur, int* __restrict__ perm, int R) {
    int g = blockIdx.x * blockDim.x + threadIdx.x;
    if (g >= E) return;
    int r = et[g];
    int lane = threadIdx.x & 63;
    for (int rr = 0; rr < R; rr++) {
        unsigned long long m = __ballot(r == rr);
        if (r == rr) {
            int leader = __ffsll((unsigned long long)m) - 1;
            int num = __popcll(m);
            int base = 0;
            if (lane == leader) base = atomicAdd(&cur[rr], num);
            base = __shfl(base, leader, 64);
            int rank = __popcll(m & ((1ull << lane) - 1ull));
            perm[base + rank] = g;
        }
    }
}

// ---- kernel 5: main — one edge per lane; wave-uniform relation -> scalar W loads ----
__global__ __launch_bounds__(256) void gather_sorted_kernel(
    const float* __restrict__ A, const int* __restrict__ ei,
    const float* __restrict__ W, const float* __restrict__ bias,
    const int* __restrict__ perm, const int* __restrict__ off,
    float* __restrict__ out, int E, int cap, int R) {
    int g = blockIdx.x * blockDim.x + threadIdx.x;
    if (g >= cap) return;

    // bucket (relation) of this slot; off[] entries are 64-aligned, so this is
    // wave-uniform. Hoist to SGPR explicitly.
    int r = 0;
    for (int rr = 1; rr < R; rr++) r += (g >= off[rr]) ? 1 : 0;
    r = __builtin_amdgcn_readfirstlane(r);

    int e = perm[g];
    bool valid = (e >= 0);
    int es = valid ? e : 0;

    int sn = ei[es];
    int dn = ei[E + es];

    const float4* As = (const float4*)(A + (size_t)sn * KDIM);
    const float4* Ad = (const float4*)(A + (size_t)dn * KDIM);
    float sv[KDIM], dv[KDIM];
#pragma unroll
    for (int q = 0; q < KDIM / 4; q++) {
        float4 s4 = As[q];
        float4 d4 = Ad[q];
        sv[4 * q + 0] = s4.x; sv[4 * q + 1] = s4.y;
        sv[4 * q + 2] = s4.z; sv[4 * q + 3] = s4.w;
        dv[4 * q + 0] = d4.x; dv[4 * q + 1] = d4.y;
        dv[4 * q + 2] = d4.z; dv[4 * q + 3] = d4.w;
    }

    const float* __restrict__ Wr = W + (size_t)r * (KDIM * KDIM);
    float total = 0.0f;
#pragma unroll
    for (int i = 0; i < KDIM; i++) {
        float acc = 0.0f;
#pragma unroll
        for (int j = 0; j < KDIM; j++) {
            acc = fmaf(Wr[i * KDIM + j], dv[j], acc);
        }
        total = fmaf(sv[i], acc, total);
    }

    if (valid) out[e] = total + bias[r];
}

// ---- fallback (no workspace): W staged in LDS, per-lane relation ----
__global__ __launch_bounds__(256) void gather_unsorted_kernel(
    const float* __restrict__ A, const int* __restrict__ ei,
    const int* __restrict__ et,
    const float* __restrict__ logits, const float* __restrict__ la,
    const float* __restrict__ bias, float* __restrict__ out, int E, int R) {
    // relation stride padded to 1032 floats: banks spread, <=2-way conflict (free)
    __shared__ float Wl[RMAX * 1032];
    int total_w = R * KDIM * KDIM;
    for (int t = threadIdx.x; t < total_w; t += blockDim.x) {
        int r = t / (KDIM * KDIM);
        int ij = t % (KDIM * KDIM);
        Wl[r * 1032 + ij] = gate_weight_(logits[t], la[t]);
    }
    __syncthreads();

    for (int e = blockIdx.x * blockDim.x + threadIdx.x; e < E;
         e += gridDim.x * blockDim.x) {
        int r = et[e];
        int sn = ei[e];
        int dn = ei[E + e];
        const float4* As = (const float4*)(A + (size_t)sn * KDIM);
        const float4* Ad = (const float4*)(A + (size_t)dn * KDIM);
        float sv[KDIM], dv[KDIM];
#pragma unroll
        for (int q = 0; q < KDIM / 4; q++) {
            float4 s4 = As[q];
            float4 d4 = Ad[q];
            sv[4 * q + 0] = s4.x; sv[4 * q + 1] = s4.y;
            sv[4 * q + 2] = s4.z; sv[4 * q + 3] = s4.w;
            dv[4 * q + 0] = d4.x; dv[4 * q + 1] = d4.y;
            dv[4 * q + 2] = d4.z; dv[4 * q + 3] = d4.w;
        }
        float totalv = 0.0f;
#pragma unroll
        for (int i = 0; i < KDIM; i++) {
            const float* Wrow = &Wl[r * 1032 + i * KDIM];
            float acc = 0.0f;
#pragma unroll
            for (int j = 0; j < KDIM / 4; j++) {
                float4 w4 = ((const float4*)Wrow)[j];
                acc = fmaf(w4.x, dv[4 * j + 0], acc);
                acc = fmaf(w4.y, dv[4 * j + 1], acc);
                acc = fmaf(w4.z, dv[4 * j + 2], acc);
                acc = fmaf(w4.w, dv[4 * j + 3], acc);
            }
            totalv = fmaf(sv[i], acc, totalv);
        }
        out[e] = totalv + bias[r];
    }
}

extern "C" void kernel_launch(void* const* d_in, const int* in_sizes, int n_in,
                              void* d_out, int out_size, void* d_ws, size_t ws_size,
                              hipStream_t stream) {
    const float* A      = (const float*)d_in[0];   // [N, 32]
    const int*   ei     = (const int*)d_in[1];     // [2, E]
    const int*   et     = (const int*)d_in[2];     // [E]
    const float* logits = (const float*)d_in[3];   // [R, 32, 32]
    const float* la     = (const float*)d_in[4];   // [R, 32, 32]
    const float* bias   = (const float*)d_in[5];   // [R]
    float* out = (float*)d_out;

    int E = in_sizes[2];
    int R = in_sizes[5];
    int n = in_sizes[3];  // R*K*K

    int cap = E + 64 * RMAX;
    size_t need = 33024 + (size_t)cap * 4;

    if (R <= RMAX && ws_size >= need) {
        char* ws = (char*)d_ws;
        float* W   = (float*)(ws);             // 32768 B
        int* cnt   = (int*)(ws + 32768);       // 32 B
        int* off   = (int*)(ws + 32832);       // 36 B
        int* cur   = (int*)(ws + 32896);       // 32 B
        int* perm  = (int*)(ws + 33024);       // cap*4 B

        hipMemsetAsync(perm, 0xFF, (size_t)cap * 4, stream);
        weights_kernel<<<(n + 255) / 256, 256, 0, stream>>>(logits, la, W, n, cnt, R);
        int hblocks = (E + 255) / 256;
        if (hblocks > 1024) hblocks = 1024;
        hist_kernel<<<hblocks, 256, 0, stream>>>(et, E, cnt, R);
        offsets_kernel<<<1, 64, 0, stream>>>(cnt, off, cur, R);
        scatter_kernel<<<(E + 255) / 256, 256, 0, stream>>>(et, E, cur, perm, R);
        gather_sorted_kernel<<<(cap + 255) / 256, 256, 0, stream>>>(
            A, ei, W, bias, perm, off, out, E, cap, R);
    } else {
        int gblocks = (E + 255) / 256;
        if (gblocks > 2048) gblocks = 2048;
        gather_unsorted_kernel<<<gblocks, 256, 0, stream>>>(
            A, ei, et, logits, la, bias, out, E, R);
    }
}

// Round 4
// 164.107 us; speedup vs baseline: 5.0864x; 5.0864x over previous
//
#include <hip/hip_runtime.h>
#include <hip/hip_bf16.h>
#include <cstdint>

#define KDIM 32
#define RMAX 8
#define NBLK 256   // blocks for hist/scatter passes

__device__ __forceinline__ float sigmoidf_(float x) {
    return 1.0f / (1.0f + expf(-x));
}

__device__ __forceinline__ float gate_weight_(float logit, float log_alpha) {
    // hard-concrete eval gate: pre = clip(la/temp, -2, 2); z = sig(pre)*1.2-0.1; clip[0,1]
    float pre = log_alpha * 1.5f;                 // / (2/3)
    pre = fminf(fmaxf(pre, -2.0f), 2.0f);
    float z = sigmoidf_(pre) * 1.2f - 0.1f;
    z = fminf(fmaxf(z, 0.0f), 1.0f);
    return sigmoidf_(logit) * z;
}

// ---- kernel 1: fused weights W[r][i][j] = sigmoid(logit) * gate(log_alpha) ----
__global__ void weights_kernel(const float* __restrict__ logits,
                               const float* __restrict__ la,
                               float* __restrict__ W, int n) {
    int g = blockIdx.x * blockDim.x + threadIdx.x;
    if (g < n) W[g] = gate_weight_(logits[g], la[g]);
}

// ---- kernel 2: per-block histogram of edge_type (LDS atomics only) ----
__global__ __launch_bounds__(256) void blockhist_kernel(
    const int* __restrict__ et, int E, int chunk,
    int* __restrict__ bh /* [NBLK][RMAX] */, int R) {
    __shared__ int h[RMAX];
    if ((int)threadIdx.x < RMAX) h[threadIdx.x] = 0;
    __syncthreads();
    int b = blockIdx.x;
    int start = b * chunk;
    int end = start + chunk;
    if (end > E) end = E;
    for (int i = start + threadIdx.x; i < end; i += blockDim.x) {
        atomicAdd(&h[et[i]], 1);
    }
    __syncthreads();
    if ((int)threadIdx.x < RMAX) bh[b * RMAX + threadIdx.x] = h[threadIdx.x];
}

// ---- kernel 3: single-block scan -> per-block bases, padded offsets, pad fill ----
__global__ __launch_bounds__(256) void scan_kernel(
    int* __restrict__ bh, int nblk, int* __restrict__ off,
    int* __restrict__ perm, int R) {
    __shared__ int cnt_s[RMAX];
    __shared__ int off_s[RMAX + 1];
    int t = threadIdx.x;
    // pass 1: exclusive prefix over blocks for each relation column
    if (t < R) {
        int running = 0;
        for (int b = 0; b < nblk; b++) {
            int v = bh[b * RMAX + t];
            bh[b * RMAX + t] = running;
            running += v;
        }
        cnt_s[t] = running;
    }
    __syncthreads();
    // padded (64-aligned) bucket offsets
    if (t == 0) {
        int o = 0;
        off_s[0] = 0;
        for (int r = 0; r < R; r++) {
            o += (cnt_s[r] + 63) & ~63;
            off_s[r + 1] = o;
        }
        for (int r = 0; r <= R; r++) off[r] = off_s[r];
    }
    __syncthreads();
    // pass 2: add bucket base to per-block prefixes
    if (t < R) {
        int base = off_s[t];
        for (int b = 0; b < nblk; b++) bh[b * RMAX + t] += base;
    }
    __syncthreads();
    // fill pad slots with -1 (<= 63 per bucket)
    for (int r = 0; r < R; r++) {
        int padStart = off_s[r] + cnt_s[r];
        int padEnd = off_s[r + 1];
        for (int i = padStart + t; i < padEnd; i += blockDim.x) perm[i] = -1;
    }
}

// ---- kernel 4: scatter via per-block LDS cursors (no global atomics) ----
__global__ __launch_bounds__(256) void scatter2_kernel(
    const int* __restrict__ et, int E, int chunk,
    const int* __restrict__ bh, int* __restrict__ perm, int R) {
    __shared__ int cur[RMAX];
    int b = blockIdx.x;
    if ((int)threadIdx.x < RMAX) cur[threadIdx.x] = bh[b * RMAX + threadIdx.x];
    __syncthreads();
    int start = b * chunk;
    int end = start + chunk;
    if (end > E) end = E;
    for (int i = start + threadIdx.x; i < end; i += blockDim.x) {
        int r = et[i];
        int pos = atomicAdd(&cur[r], 1);
        perm[pos] = i;
    }
}

// ---- kernel 5: main — one edge per lane; wave-uniform relation -> scalar W loads ----
__global__ __launch_bounds__(256) void gather_sorted_kernel(
    const float* __restrict__ A, const int* __restrict__ ei,
    const float* __restrict__ W, const float* __restrict__ bias,
    const int* __restrict__ perm, const int* __restrict__ off,
    float* __restrict__ out, int E, int cap, int R) {
    int g = blockIdx.x * blockDim.x + threadIdx.x;
    if (g >= cap) return;

    // bucket (relation) of this slot; off[] entries are 64-aligned, so this is
    // wave-uniform. Hoist to SGPR explicitly.
    int r = 0;
    for (int rr = 1; rr < R; rr++) r += (g >= off[rr]) ? 1 : 0;
    r = __builtin_amdgcn_readfirstlane(r);

    int e = perm[g];
    bool valid = (e >= 0);
    int es = valid ? e : 0;

    int sn = ei[es];
    int dn = ei[E + es];

    const float4* As = (const float4*)(A + (size_t)sn * KDIM);
    const float4* Ad = (const float4*)(A + (size_t)dn * KDIM);
    float sv[KDIM], dv[KDIM];
#pragma unroll
    for (int q = 0; q < KDIM / 4; q++) {
        float4 s4 = As[q];
        float4 d4 = Ad[q];
        sv[4 * q + 0] = s4.x; sv[4 * q + 1] = s4.y;
        sv[4 * q + 2] = s4.z; sv[4 * q + 3] = s4.w;
        dv[4 * q + 0] = d4.x; dv[4 * q + 1] = d4.y;
        dv[4 * q + 2] = d4.z; dv[4 * q + 3] = d4.w;
    }

    const float* __restrict__ Wr = W + (size_t)r * (KDIM * KDIM);
    float total = 0.0f;
#pragma unroll
    for (int i = 0; i < KDIM; i++) {
        float acc = 0.0f;
#pragma unroll
        for (int j = 0; j < KDIM; j++) {
            acc = fmaf(Wr[i * KDIM + j], dv[j], acc);
        }
        total = fmaf(sv[i], acc, total);
    }

    if (valid) out[e] = total + bias[r];
}

// ---- fallback (no workspace): W staged in LDS, per-lane relation ----
__global__ __launch_bounds__(256) void gather_unsorted_kernel(
    const float* __restrict__ A, const int* __restrict__ ei,
    const int* __restrict__ et,
    const float* __restrict__ logits, const float* __restrict__ la,
    const float* __restrict__ bias, float* __restrict__ out, int E, int R) {
    // relation stride padded to 1032 floats: banks spread, <=2-way conflict (free)
    __shared__ float Wl[RMAX * 1032];
    int total_w = R * KDIM * KDIM;
    for (int t = threadIdx.x; t < total_w; t += blockDim.x) {
        int r = t / (KDIM * KDIM);
        int ij = t % (KDIM * KDIM);
        Wl[r * 1032 + ij] = gate_weight_(logits[t], la[t]);
    }
    __syncthreads();

    for (int e = blockIdx.x * blockDim.x + threadIdx.x; e < E;
         e += gridDim.x * blockDim.x) {
        int r = et[e];
        int sn = ei[e];
        int dn = ei[E + e];
        const float4* As = (const float4*)(A + (size_t)sn * KDIM);
        const float4* Ad = (const float4*)(A + (size_t)dn * KDIM);
        float sv[KDIM], dv[KDIM];
#pragma unroll
        for (int q = 0; q < KDIM / 4; q++) {
            float4 s4 = As[q];
            float4 d4 = Ad[q];
            sv[4 * q + 0] = s4.x; sv[4 * q + 1] = s4.y;
            sv[4 * q + 2] = s4.z; sv[4 * q + 3] = s4.w;
            dv[4 * q + 0] = d4.x; dv[4 * q + 1] = d4.y;
            dv[4 * q + 2] = d4.z; dv[4 * q + 3] = d4.w;
        }
        float totalv = 0.0f;
#pragma unroll
        for (int i = 0; i < KDIM; i++) {
            const float* Wrow = &Wl[r * 1032 + i * KDIM];
            float acc = 0.0f;
#pragma unroll
            for (int j = 0; j < KDIM / 4; j++) {
                float4 w4 = ((const float4*)Wrow)[j];
                acc = fmaf(w4.x, dv[4 * j + 0], acc);
                acc = fmaf(w4.y, dv[4 * j + 1], acc);
                acc = fmaf(w4.z, dv[4 * j + 2], acc);
                acc = fmaf(w4.w, dv[4 * j + 3], acc);
            }
            totalv = fmaf(sv[i], acc, totalv);
        }
        out[e] = totalv + bias[r];
    }
}

extern "C" void kernel_launch(void* const* d_in, const int* in_sizes, int n_in,
                              void* d_out, int out_size, void* d_ws, size_t ws_size,
                              hipStream_t stream) {
    const float* A      = (const float*)d_in[0];   // [N, 32]
    const int*   ei     = (const int*)d_in[1];     // [2, E]
    const int*   et     = (const int*)d_in[2];     // [E]
    const float* logits = (const float*)d_in[3];   // [R, 32, 32]
    const float* la     = (const float*)d_in[4];   // [R, 32, 32]
    const float* bias   = (const float*)d_in[5];   // [R]
    float* out = (float*)d_out;

    int E = in_sizes[2];
    int R = in_sizes[5];
    int n = in_sizes[3];  // R*K*K

    int cap = E + 64 * RMAX;
    // ws layout: W (32768) | off (64) | bh (NBLK*RMAX*4 = 8192) | perm (cap*4)
    size_t need = 32768 + 64 + (size_t)NBLK * RMAX * 4 + (size_t)cap * 4;

    if (R <= RMAX && ws_size >= need) {
        char* ws = (char*)d_ws;
        float* W  = (float*)(ws);
        int* off  = (int*)(ws + 32768);
        int* bh   = (int*)(ws + 32768 + 64);
        int* perm = (int*)(ws + 32768 + 64 + NBLK * RMAX * 4);

        int chunk = (E + NBLK - 1) / NBLK;

        weights_kernel<<<(n + 255) / 256, 256, 0, stream>>>(logits, la, W, n);
        blockhist_kernel<<<NBLK, 256, 0, stream>>>(et, E, chunk, bh, R);
        scan_kernel<<<1, 256, 0, stream>>>(bh, NBLK, off, perm, R);
        scatter2_kernel<<<NBLK, 256, 0, stream>>>(et, E, chunk, bh, perm, R);
        gather_sorted_kernel<<<(cap + 255) / 256, 256, 0, stream>>>(
            A, ei, W, bias, perm, off, out, E, cap, R);
    } else {
        int gblocks = (E + 255) / 256;
        if (gblocks > 2048) gblocks = 2048;
        gather_unsorted_kernel<<<gblocks, 256, 0, stream>>>(
            A, ei, et, logits, la, bias, out, E, R);
    }
}

// Round 5
// 120.258 us; speedup vs baseline: 6.9410x; 1.3646x over previous
//
#include <hip/hip_runtime.h>
#include <hip/hip_bf16.h>
#include <cstdint>

#define KDIM 32
#define RMAX 8
#define NBLK 256   // blocks for hist/scatter passes

__device__ __forceinline__ float sigmoidf_(float x) {
    return 1.0f / (1.0f + expf(-x));
}

__device__ __forceinline__ float gate_weight_(float logit, float log_alpha) {
    // hard-concrete eval gate: pre = clip(la/temp, -2, 2); z = sig(pre)*1.2-0.1; clip[0,1]
    float pre = log_alpha * 1.5f;                 // / (2/3)
    pre = fminf(fmaxf(pre, -2.0f), 2.0f);
    float z = sigmoidf_(pre) * 1.2f - 0.1f;
    z = fminf(fmaxf(z, 0.0f), 1.0f);
    return sigmoidf_(logit) * z;
}

// ---- kernel 1: fused weights W[r][i][j] = sigmoid(logit) * gate(log_alpha) ----
__global__ void weights_kernel(const float* __restrict__ logits,
                               const float* __restrict__ la,
                               float* __restrict__ W, int n) {
    int g = blockIdx.x * blockDim.x + threadIdx.x;
    if (g < n) W[g] = gate_weight_(logits[g], la[g]);
}

// ---- kernel 2: per-block histogram of edge_type (LDS atomics only) ----
__global__ __launch_bounds__(256) void blockhist_kernel(
    const int* __restrict__ et, int E, int chunk,
    int* __restrict__ bh /* [NBLK][RMAX] */, int R) {
    __shared__ int h[RMAX];
    if ((int)threadIdx.x < RMAX) h[threadIdx.x] = 0;
    __syncthreads();
    int b = blockIdx.x;
    int start = b * chunk;
    int end = start + chunk;
    if (end > E) end = E;
    for (int i = start + threadIdx.x; i < end; i += blockDim.x) {
        atomicAdd(&h[et[i]], 1);
    }
    __syncthreads();
    if ((int)threadIdx.x < RMAX) bh[b * RMAX + threadIdx.x] = h[threadIdx.x];
}

// ---- kernel 3: PARALLEL scan (1 block, 512 threads = 8 waves) ----
// wave r scans relation r's column over the 256 block-histograms via
// in-register partials + shfl_up wave scan. Also computes padded bucket
// offsets and fills pad slots with -1.
__global__ __launch_bounds__(512) void scan2_kernel(
    int* __restrict__ bh, int* __restrict__ off,
    int* __restrict__ perm, int R) {
    __shared__ int tr[RMAX][NBLK];     // transposed histograms, 8 KB
    __shared__ int cnt_s[RMAX];
    __shared__ int off_s[RMAX + 1];
    int t = threadIdx.x;

    // coalesced load + transpose
    for (int i = t; i < NBLK * RMAX; i += 512) {
        int b = i / RMAX, r = i % RMAX;
        tr[r][b] = bh[i];
    }
    __syncthreads();

    int w = t >> 6;        // wave id = relation
    int lane = t & 63;
    if (w < R) {
        int b0 = lane * 4;
        int v0 = tr[w][b0 + 0];
        int v1 = tr[w][b0 + 1];
        int v2 = tr[w][b0 + 2];
        int v3 = tr[w][b0 + 3];
        int s0 = v0, s1 = s0 + v1, s2 = s1 + v2, s3 = s2 + v3;
        int lanesum = s3;
        int sc = lanesum;
#pragma unroll
        for (int d = 1; d < 64; d <<= 1) {
            int up = __shfl_up(sc, d, 64);
            if (lane >= d) sc += up;
        }
        int excl = sc - lanesum;       // exclusive prefix of this lane's chunk
        tr[w][b0 + 0] = excl;
        tr[w][b0 + 1] = excl + s0;
        tr[w][b0 + 2] = excl + s1;
        tr[w][b0 + 3] = excl + s2;
        if (lane == 63) cnt_s[w] = sc; // bucket total
    }
    __syncthreads();

    if (t == 0) {
        int o = 0;
        off_s[0] = 0;
        for (int r = 0; r < R; r++) {
            o += (cnt_s[r] + 63) & ~63;
            off_s[r + 1] = o;
        }
        for (int r = 0; r <= R; r++) off[r] = off_s[r];
    }
    __syncthreads();

    // write back per-block bases (bucket base + exclusive prefix), coalesced
    for (int i = t; i < NBLK * RMAX; i += 512) {
        int b = i / RMAX, r = i % RMAX;
        bh[i] = tr[r][b] + ((r < R) ? off_s[r] : 0);
    }
    // fill pad slots with -1 (<= 63 per bucket)
    for (int r = 0; r < R; r++) {
        int padStart = off_s[r] + cnt_s[r];
        int padEnd = off_s[r + 1];
        for (int i = padStart + t; i < padEnd; i += 512) perm[i] = -1;
    }
}

// ---- kernel 4: scatter via per-block LDS cursors (no global atomics) ----
__global__ __launch_bounds__(256) void scatter2_kernel(
    const int* __restrict__ et, int E, int chunk,
    const int* __restrict__ bh, int* __restrict__ perm, int R) {
    __shared__ int cur[RMAX];
    int b = blockIdx.x;
    if ((int)threadIdx.x < RMAX) cur[threadIdx.x] = bh[b * RMAX + threadIdx.x];
    __syncthreads();
    int start = b * chunk;
    int end = start + chunk;
    if (end > E) end = E;
    for (int i = start + threadIdx.x; i < end; i += blockDim.x) {
        int r = et[i];
        int pos = atomicAdd(&cur[r], 1);
        perm[pos] = i;
    }
}

// ---- kernel 5: main — one edge per lane; wave-uniform relation -> scalar W loads ----
__global__ __launch_bounds__(256) void gather_sorted_kernel(
    const float* __restrict__ A, const int* __restrict__ ei,
    const float* __restrict__ W, const float* __restrict__ bias,
    const int* __restrict__ perm, const int* __restrict__ off,
    float* __restrict__ out, int E, int cap, int R) {
    int g = blockIdx.x * blockDim.x + threadIdx.x;
    if (g >= cap) return;

    // bucket (relation) of this slot; off[] entries are 64-aligned, so this is
    // wave-uniform. Hoist to SGPR explicitly.
    int r = 0;
    for (int rr = 1; rr < R; rr++) r += (g >= off[rr]) ? 1 : 0;
    r = __builtin_amdgcn_readfirstlane(r);

    int e = perm[g];
    bool valid = (e >= 0);
    int es = valid ? e : 0;

    int sn = ei[es];
    int dn = ei[E + es];

    const float4* As = (const float4*)(A + (size_t)sn * KDIM);
    const float4* Ad = (const float4*)(A + (size_t)dn * KDIM);
    float sv[KDIM], dv[KDIM];
#pragma unroll
    for (int q = 0; q < KDIM / 4; q++) {
        float4 s4 = As[q];
        float4 d4 = Ad[q];
        sv[4 * q + 0] = s4.x; sv[4 * q + 1] = s4.y;
        sv[4 * q + 2] = s4.z; sv[4 * q + 3] = s4.w;
        dv[4 * q + 0] = d4.x; dv[4 * q + 1] = d4.y;
        dv[4 * q + 2] = d4.z; dv[4 * q + 3] = d4.w;
    }

    const float* __restrict__ Wr = W + (size_t)r * (KDIM * KDIM);
    float total = 0.0f;
#pragma unroll
    for (int i = 0; i < KDIM; i++) {
        float acc = 0.0f;
#pragma unroll
        for (int j = 0; j < KDIM; j++) {
            acc = fmaf(Wr[i * KDIM + j], dv[j], acc);
        }
        total = fmaf(sv[i], acc, total);
    }

    if (valid) out[e] = total + bias[r];
}

// ---- fallback (no workspace): W staged in LDS, per-lane relation ----
__global__ __launch_bounds__(256) void gather_unsorted_kernel(
    const float* __restrict__ A, const int* __restrict__ ei,
    const int* __restrict__ et,
    const float* __restrict__ logits, const float* __restrict__ la,
    const float* __restrict__ bias, float* __restrict__ out, int E, int R) {
    // relation stride padded to 1032 floats: banks spread, <=2-way conflict (free)
    __shared__ float Wl[RMAX * 1032];
    int total_w = R * KDIM * KDIM;
    for (int t = threadIdx.x; t < total_w; t += blockDim.x) {
        int r = t / (KDIM * KDIM);
        int ij = t % (KDIM * KDIM);
        Wl[r * 1032 + ij] = gate_weight_(logits[t], la[t]);
    }
    __syncthreads();

    for (int e = blockIdx.x * blockDim.x + threadIdx.x; e < E;
         e += gridDim.x * blockDim.x) {
        int r = et[e];
        int sn = ei[e];
        int dn = ei[E + e];
        const float4* As = (const float4*)(A + (size_t)sn * KDIM);
        const float4* Ad = (const float4*)(A + (size_t)dn * KDIM);
        float sv[KDIM], dv[KDIM];
#pragma unroll
        for (int q = 0; q < KDIM / 4; q++) {
            float4 s4 = As[q];
            float4 d4 = Ad[q];
            sv[4 * q + 0] = s4.x; sv[4 * q + 1] = s4.y;
            sv[4 * q + 2] = s4.z; sv[4 * q + 3] = s4.w;
            dv[4 * q + 0] = d4.x; dv[4 * q + 1] = d4.y;
            dv[4 * q + 2] = d4.z; dv[4 * q + 3] = d4.w;
        }
        float totalv = 0.0f;
#pragma unroll
        for (int i = 0; i < KDIM; i++) {
            const float* Wrow = &Wl[r * 1032 + i * KDIM];
            float acc = 0.0f;
#pragma unroll
            for (int j = 0; j < KDIM / 4; j++) {
                float4 w4 = ((const float4*)Wrow)[j];
                acc = fmaf(w4.x, dv[4 * j + 0], acc);
                acc = fmaf(w4.y, dv[4 * j + 1], acc);
                acc = fmaf(w4.z, dv[4 * j + 2], acc);
                acc = fmaf(w4.w, dv[4 * j + 3], acc);
            }
            totalv = fmaf(sv[i], acc, totalv);
        }
        out[e] = totalv + bias[r];
    }
}

extern "C" void kernel_launch(void* const* d_in, const int* in_sizes, int n_in,
                              void* d_out, int out_size, void* d_ws, size_t ws_size,
                              hipStream_t stream) {
    const float* A      = (const float*)d_in[0];   // [N, 32]
    const int*   ei     = (const int*)d_in[1];     // [2, E]
    const int*   et     = (const int*)d_in[2];     // [E]
    const float* logits = (const float*)d_in[3];   // [R, 32, 32]
    const float* la     = (const float*)d_in[4];   // [R, 32, 32]
    const float* bias   = (const float*)d_in[5];   // [R]
    float* out = (float*)d_out;

    int E = in_sizes[2];
    int R = in_sizes[5];
    int n = in_sizes[3];  // R*K*K

    int cap = E + 64 * RMAX;
    // ws layout: W (32768) | off (64) | bh (NBLK*RMAX*4 = 8192) | perm (cap*4)
    size_t need = 32768 + 64 + (size_t)NBLK * RMAX * 4 + (size_t)cap * 4;

    if (R <= RMAX && ws_size >= need) {
        char* ws = (char*)d_ws;
        float* W  = (float*)(ws);
        int* off  = (int*)(ws + 32768);
        int* bh   = (int*)(ws + 32768 + 64);
        int* perm = (int*)(ws + 32768 + 64 + NBLK * RMAX * 4);

        int chunk = (E + NBLK - 1) / NBLK;

        weights_kernel<<<(n + 255) / 256, 256, 0, stream>>>(logits, la, W, n);
        blockhist_kernel<<<NBLK, 256, 0, stream>>>(et, E, chunk, bh, R);
        scan2_kernel<<<1, 512, 0, stream>>>(bh, off, perm, R);
        scatter2_kernel<<<NBLK, 256, 0, stream>>>(et, E, chunk, bh, perm, R);
        gather_sorted_kernel<<<(cap + 255) / 256, 256, 0, stream>>>(
            A, ei, W, bias, perm, off, out, E, cap, R);
    } else {
        int gblocks = (E + 255) / 256;
        if (gblocks > 2048) gblocks = 2048;
        gather_unsorted_kernel<<<gblocks, 256, 0, stream>>>(
            A, ei, et, logits, la, bias, out, E, R);
    }
}

// Round 6
// 118.818 us; speedup vs baseline: 7.0251x; 1.0121x over previous
//
#include <hip/hip_runtime.h>
#include <hip/hip_bf16.h>
#include <cstdint>

#define KDIM 32
#define RMAX 8
#define NBLK 256   // blocks for hist/scatter passes

__device__ __forceinline__ float sigmoidf_(float x) {
    return 1.0f / (1.0f + expf(-x));
}

__device__ __forceinline__ float gate_weight_(float logit, float log_alpha) {
    // hard-concrete eval gate: pre = clip(la/temp, -2, 2); z = sig(pre)*1.2-0.1; clip[0,1]
    float pre = log_alpha * 1.5f;                 // / (2/3)
    pre = fminf(fmaxf(pre, -2.0f), 2.0f);
    float z = sigmoidf_(pre) * 1.2f - 0.1f;
    z = fminf(fmaxf(z, 0.0f), 1.0f);
    return sigmoidf_(logit) * z;
}

// ---- kernel 1: per-block histogram of edge_type (LDS atomics only),
//      with the tiny fused-weights pass folded into the same dispatch ----
__global__ __launch_bounds__(256) void blockhist_weights_kernel(
    const int* __restrict__ et, int E, int chunk,
    int* __restrict__ bh /* [NBLK][RMAX] */, int R,
    const float* __restrict__ logits, const float* __restrict__ la,
    float* __restrict__ W, int n) {
    // fused weights: first n global threads (n = R*K*K = 8192 << grid size)
    int g = blockIdx.x * blockDim.x + threadIdx.x;
    if (g < n) W[g] = gate_weight_(logits[g], la[g]);

    __shared__ int h[RMAX];
    if ((int)threadIdx.x < RMAX) h[threadIdx.x] = 0;
    __syncthreads();
    int b = blockIdx.x;
    int start = b * chunk;
    int end = start + chunk;
    if (end > E) end = E;
    for (int i = start + threadIdx.x; i < end; i += blockDim.x) {
        atomicAdd(&h[et[i]], 1);
    }
    __syncthreads();
    if ((int)threadIdx.x < RMAX) bh[b * RMAX + threadIdx.x] = h[threadIdx.x];
}

// ---- kernel 2: PARALLEL scan (1 block, 512 threads = 8 waves) ----
// wave r scans relation r's column over the 256 block-histograms via
// in-register partials + shfl_up wave scan. Also computes padded bucket
// offsets and marks pad-slot records invalid (e = -1).
__global__ __launch_bounds__(512) void scan2_kernel(
    int* __restrict__ bh, int* __restrict__ off,
    int4* __restrict__ edata, int R) {
    __shared__ int tr[RMAX][NBLK];     // transposed histograms, 8 KB
    __shared__ int cnt_s[RMAX];
    __shared__ int off_s[RMAX + 1];
    int t = threadIdx.x;

    // coalesced load + transpose
    for (int i = t; i < NBLK * RMAX; i += 512) {
        int b = i / RMAX, r = i % RMAX;
        tr[r][b] = bh[i];
    }
    __syncthreads();

    int w = t >> 6;        // wave id = relation
    int lane = t & 63;
    if (w < R) {
        int b0 = lane * 4;
        int v0 = tr[w][b0 + 0];
        int v1 = tr[w][b0 + 1];
        int v2 = tr[w][b0 + 2];
        int v3 = tr[w][b0 + 3];
        int s0 = v0, s1 = s0 + v1, s2 = s1 + v2, s3 = s2 + v3;
        int lanesum = s3;
        int sc = lanesum;
#pragma unroll
        for (int d = 1; d < 64; d <<= 1) {
            int up = __shfl_up(sc, d, 64);
            if (lane >= d) sc += up;
        }
        int excl = sc - lanesum;       // exclusive prefix of this lane's chunk
        tr[w][b0 + 0] = excl;
        tr[w][b0 + 1] = excl + s0;
        tr[w][b0 + 2] = excl + s1;
        tr[w][b0 + 3] = excl + s2;
        if (lane == 63) cnt_s[w] = sc; // bucket total
    }
    __syncthreads();

    if (t == 0) {
        int o = 0;
        off_s[0] = 0;
        for (int r = 0; r < R; r++) {
            o += (cnt_s[r] + 63) & ~63;
            off_s[r + 1] = o;
        }
        for (int r = 0; r <= R; r++) off[r] = off_s[r];
    }
    __syncthreads();

    // write back per-block bases (bucket base + exclusive prefix), coalesced
    for (int i = t; i < NBLK * RMAX; i += 512) {
        int b = i / RMAX, r = i % RMAX;
        bh[i] = tr[r][b] + ((r < R) ? off_s[r] : 0);
    }
    // mark pad slots invalid (<= 63 per bucket)
    for (int r = 0; r < R; r++) {
        int padStart = off_s[r] + cnt_s[r];
        int padEnd = off_s[r + 1];
        for (int i = padStart + t; i < padEnd; i += 512) {
            edata[i] = make_int4(0, 0, -1, 0);
        }
    }
}

// ---- kernel 3: scatter packed records {src, dst, e} via per-block LDS
//      cursors (no global atomics); ei read coalesced here so the gather
//      kernel needs no dependent random index loads ----
__global__ __launch_bounds__(256) void scatter3_kernel(
    const int* __restrict__ et, const int* __restrict__ ei, int E, int chunk,
    const int* __restrict__ bh, int4* __restrict__ edata, int R) {
    __shared__ int cur[RMAX];
    int b = blockIdx.x;
    if ((int)threadIdx.x < RMAX) cur[threadIdx.x] = bh[b * RMAX + threadIdx.x];
    __syncthreads();
    int start = b * chunk;
    int end = start + chunk;
    if (end > E) end = E;
    for (int i = start + threadIdx.x; i < end; i += blockDim.x) {
        int r = et[i];
        int sn = ei[i];
        int dn = ei[E + i];
        int pos = atomicAdd(&cur[r], 1);
        edata[pos] = make_int4(sn, dn, i, 0);
    }
}

// ---- kernel 4: main — one edge per lane; wave-uniform relation -> scalar W loads ----
__global__ __launch_bounds__(256) void gather2_kernel(
    const float* __restrict__ A, const float* __restrict__ W,
    const float* __restrict__ bias, const int4* __restrict__ edata,
    const int* __restrict__ off, float* __restrict__ out, int cap, int R) {
    int g = blockIdx.x * blockDim.x + threadIdx.x;
    if (g >= cap) return;

    // bucket (relation) of this slot; off[] entries are 64-aligned, so this is
    // wave-uniform. Hoist to SGPR explicitly.
    int r = 0;
    for (int rr = 1; rr < R; rr++) r += (g >= off[rr]) ? 1 : 0;
    r = __builtin_amdgcn_readfirstlane(r);

    int4 rec = edata[g];               // coalesced 16 B/lane
    bool valid = (rec.z >= 0);
    int sn = valid ? rec.x : 0;        // clamp: pad slots & poison tail
    int dn = valid ? rec.y : 0;

    const float4* As = (const float4*)(A + (size_t)sn * KDIM);
    const float4* Ad = (const float4*)(A + (size_t)dn * KDIM);
    float sv[KDIM], dv[KDIM];
#pragma unroll
    for (int q = 0; q < KDIM / 4; q++) {
        float4 s4 = As[q];
        float4 d4 = Ad[q];
        sv[4 * q + 0] = s4.x; sv[4 * q + 1] = s4.y;
        sv[4 * q + 2] = s4.z; sv[4 * q + 3] = s4.w;
        dv[4 * q + 0] = d4.x; dv[4 * q + 1] = d4.y;
        dv[4 * q + 2] = d4.z; dv[4 * q + 3] = d4.w;
    }

    const float* __restrict__ Wr = W + (size_t)r * (KDIM * KDIM);
    float total = 0.0f;
#pragma unroll
    for (int i = 0; i < KDIM; i++) {
        float acc = 0.0f;
#pragma unroll
        for (int j = 0; j < KDIM; j++) {
            acc = fmaf(Wr[i * KDIM + j], dv[j], acc);
        }
        total = fmaf(sv[i], acc, total);
    }

    if (valid) out[rec.z] = total + bias[r];
}

// ---- fallback (no workspace): W staged in LDS, per-lane relation ----
__global__ __launch_bounds__(256) void gather_unsorted_kernel(
    const float* __restrict__ A, const int* __restrict__ ei,
    const int* __restrict__ et,
    const float* __restrict__ logits, const float* __restrict__ la,
    const float* __restrict__ bias, float* __restrict__ out, int E, int R) {
    // relation stride padded to 1032 floats: banks spread, <=2-way conflict (free)
    __shared__ float Wl[RMAX * 1032];
    int total_w = R * KDIM * KDIM;
    for (int t = threadIdx.x; t < total_w; t += blockDim.x) {
        int r = t / (KDIM * KDIM);
        int ij = t % (KDIM * KDIM);
        Wl[r * 1032 + ij] = gate_weight_(logits[t], la[t]);
    }
    __syncthreads();

    for (int e = blockIdx.x * blockDim.x + threadIdx.x; e < E;
         e += gridDim.x * blockDim.x) {
        int r = et[e];
        int sn = ei[e];
        int dn = ei[E + e];
        const float4* As = (const float4*)(A + (size_t)sn * KDIM);
        const float4* Ad = (const float4*)(A + (size_t)dn * KDIM);
        float sv[KDIM], dv[KDIM];
#pragma unroll
        for (int q = 0; q < KDIM / 4; q++) {
            float4 s4 = As[q];
            float4 d4 = Ad[q];
            sv[4 * q + 0] = s4.x; sv[4 * q + 1] = s4.y;
            sv[4 * q + 2] = s4.z; sv[4 * q + 3] = s4.w;
            dv[4 * q + 0] = d4.x; dv[4 * q + 1] = d4.y;
            dv[4 * q + 2] = d4.z; dv[4 * q + 3] = d4.w;
        }
        float totalv = 0.0f;
#pragma unroll
        for (int i = 0; i < KDIM; i++) {
            const float* Wrow = &Wl[r * 1032 + i * KDIM];
            float acc = 0.0f;
#pragma unroll
            for (int j = 0; j < KDIM / 4; j++) {
                float4 w4 = ((const float4*)Wrow)[j];
                acc = fmaf(w4.x, dv[4 * j + 0], acc);
                acc = fmaf(w4.y, dv[4 * j + 1], acc);
                acc = fmaf(w4.z, dv[4 * j + 2], acc);
                acc = fmaf(w4.w, dv[4 * j + 3], acc);
            }
            totalv = fmaf(sv[i], acc, totalv);
        }
        out[e] = totalv + bias[r];
    }
}

extern "C" void kernel_launch(void* const* d_in, const int* in_sizes, int n_in,
                              void* d_out, int out_size, void* d_ws, size_t ws_size,
                              hipStream_t stream) {
    const float* A      = (const float*)d_in[0];   // [N, 32]
    const int*   ei     = (const int*)d_in[1];     // [2, E]
    const int*   et     = (const int*)d_in[2];     // [E]
    const float* logits = (const float*)d_in[3];   // [R, 32, 32]
    const float* la     = (const float*)d_in[4];   // [R, 32, 32]
    const float* bias   = (const float*)d_in[5];   // [R]
    float* out = (float*)d_out;

    int E = in_sizes[2];
    int R = in_sizes[5];
    int n = in_sizes[3];  // R*K*K

    int cap = E + 64 * RMAX;
    // ws layout: W (32768) | off (64) | bh (8192) | edata (cap*16)
    size_t need = 32768 + 64 + (size_t)NBLK * RMAX * 4 + (size_t)cap * 16;

    if (R <= RMAX && ws_size >= need) {
        char* ws = (char*)d_ws;
        float* W    = (float*)(ws);
        int* off    = (int*)(ws + 32768);
        int* bh     = (int*)(ws + 32768 + 64);
        int4* edata = (int4*)(ws + 32768 + 64 + NBLK * RMAX * 4);

        int chunk = (E + NBLK - 1) / NBLK;

        blockhist_weights_kernel<<<NBLK, 256, 0, stream>>>(
            et, E, chunk, bh, R, logits, la, W, n);
        scan2_kernel<<<1, 512, 0, stream>>>(bh, off, edata, R);
        scatter3_kernel<<<NBLK, 256, 0, stream>>>(et, ei, E, chunk, bh, edata, R);
        gather2_kernel<<<(cap + 255) / 256, 256, 0, stream>>>(
            A, W, bias, edata, off, out, cap, R);
    } else {
        int gblocks = (E + 255) / 256;
        if (gblocks > 2048) gblocks = 2048;
        gather_unsorted_kernel<<<gblocks, 256, 0, stream>>>(
            A, ei, et, logits, la, bias, out, E, R);
    }
}

// Round 7
// 108.129 us; speedup vs baseline: 7.7195x; 1.0989x over previous
//
#include <hip/hip_runtime.h>
#include <hip/hip_bf16.h>
#include <cstdint>

#define KDIM 32
#define RMAX 8
#define NBLK 256   // blocks for hist/scatter passes

typedef _Float16 half2v __attribute__((ext_vector_type(2)));

__device__ __forceinline__ float sigmoidf_(float x) {
    return 1.0f / (1.0f + expf(-x));
}

__device__ __forceinline__ float gate_weight_(float logit, float log_alpha) {
    // hard-concrete eval gate: pre = clip(la/temp, -2, 2); z = sig(pre)*1.2-0.1; clip[0,1]
    float pre = log_alpha * 1.5f;                 // / (2/3)
    pre = fminf(fmaxf(pre, -2.0f), 2.0f);
    float z = sigmoidf_(pre) * 1.2f - 0.1f;
    z = fminf(fmaxf(z, 0.0f), 1.0f);
    return sigmoidf_(logit) * z;
}

// ---- kernel 1: per-block histogram + W->f16 + A->f16 conversion ----
__global__ __launch_bounds__(256) void prep_kernel(
    const int* __restrict__ et, int E, int chunk,
    int* __restrict__ bh /* [NBLK][RMAX] */, int R,
    const float* __restrict__ logits, const float* __restrict__ la,
    _Float16* __restrict__ Wh, int n,
    const float* __restrict__ A, _Float16* __restrict__ Ah, int nA) {
    int g = blockIdx.x * blockDim.x + threadIdx.x;
    // fused gate weights -> f16 (n = R*K*K = 8192 << grid)
    if (g < n) Wh[g] = (_Float16)gate_weight_(logits[g], la[g]);

    // A fp32 -> f16 table, coalesced grid-stride over float4 groups
    int nthreads = gridDim.x * blockDim.x;
    int n4 = nA >> 2;
    for (int i4 = g; i4 < n4; i4 += nthreads) {
        float4 v = ((const float4*)A)[i4];
        half2v h0; h0[0] = (_Float16)v.x; h0[1] = (_Float16)v.y;
        half2v h1; h1[0] = (_Float16)v.z; h1[1] = (_Float16)v.w;
        ((half2v*)Ah)[i4 * 2 + 0] = h0;
        ((half2v*)Ah)[i4 * 2 + 1] = h1;
    }

    __shared__ int h[RMAX];
    if ((int)threadIdx.x < RMAX) h[threadIdx.x] = 0;
    __syncthreads();
    int b = blockIdx.x;
    int start = b * chunk;
    int end = start + chunk;
    if (end > E) end = E;
    for (int i = start + threadIdx.x; i < end; i += blockDim.x) {
        atomicAdd(&h[et[i]], 1);
    }
    __syncthreads();
    if ((int)threadIdx.x < RMAX) bh[b * RMAX + threadIdx.x] = h[threadIdx.x];
}

// ---- kernel 2: PARALLEL scan (1 block, 512 threads = 8 waves) ----
__global__ __launch_bounds__(512) void scan2_kernel(
    int* __restrict__ bh, int* __restrict__ off,
    int4* __restrict__ edata, int R) {
    __shared__ int tr[RMAX][NBLK];     // transposed histograms, 8 KB
    __shared__ int cnt_s[RMAX];
    __shared__ int off_s[RMAX + 1];
    int t = threadIdx.x;

    for (int i = t; i < NBLK * RMAX; i += 512) {
        int b = i / RMAX, r = i % RMAX;
        tr[r][b] = bh[i];
    }
    __syncthreads();

    int w = t >> 6;        // wave id = relation
    int lane = t & 63;
    if (w < R) {
        int b0 = lane * 4;
        int v0 = tr[w][b0 + 0];
        int v1 = tr[w][b0 + 1];
        int v2 = tr[w][b0 + 2];
        int v3 = tr[w][b0 + 3];
        int s0 = v0, s1 = s0 + v1, s2 = s1 + v2, s3 = s2 + v3;
        int lanesum = s3;
        int sc = lanesum;
#pragma unroll
        for (int d = 1; d < 64; d <<= 1) {
            int up = __shfl_up(sc, d, 64);
            if (lane >= d) sc += up;
        }
        int excl = sc - lanesum;
        tr[w][b0 + 0] = excl;
        tr[w][b0 + 1] = excl + s0;
        tr[w][b0 + 2] = excl + s1;
        tr[w][b0 + 3] = excl + s2;
        if (lane == 63) cnt_s[w] = sc;
    }
    __syncthreads();

    if (t == 0) {
        int o = 0;
        off_s[0] = 0;
        for (int r = 0; r < R; r++) {
            o += (cnt_s[r] + 63) & ~63;
            off_s[r + 1] = o;
        }
        for (int r = 0; r <= R; r++) off[r] = off_s[r];
    }
    __syncthreads();

    for (int i = t; i < NBLK * RMAX; i += 512) {
        int b = i / RMAX, r = i % RMAX;
        bh[i] = tr[r][b] + ((r < R) ? off_s[r] : 0);
    }
    for (int r = 0; r < R; r++) {
        int padStart = off_s[r] + cnt_s[r];
        int padEnd = off_s[r + 1];
        for (int i = padStart + t; i < padEnd; i += 512) {
            edata[i] = make_int4(0, 0, -1, 0);
        }
    }
}

// ---- kernel 3: scatter packed records {src, dst, e} via per-block LDS cursors ----
__global__ __launch_bounds__(256) void scatter3_kernel(
    const int* __restrict__ et, const int* __restrict__ ei, int E, int chunk,
    const int* __restrict__ bh, int4* __restrict__ edata, int R) {
    __shared__ int cur[RMAX];
    int b = blockIdx.x;
    if ((int)threadIdx.x < RMAX) cur[threadIdx.x] = bh[b * RMAX + threadIdx.x];
    __syncthreads();
    int start = b * chunk;
    int end = start + chunk;
    if (end > E) end = E;
    for (int i = start + threadIdx.x; i < end; i += blockDim.x) {
        int r = et[i];
        int sn = ei[i];
        int dn = ei[E + i];
        int pos = atomicAdd(&cur[r], 1);
        edata[pos] = make_int4(sn, dn, i, 0);
    }
}

// ---- kernel 4: main — one edge per lane; wave-uniform relation; f16 dot2 ----
__global__ __launch_bounds__(256) void gather3_kernel(
    const _Float16* __restrict__ Ah, const _Float16* __restrict__ Wh,
    const float* __restrict__ bias, const int4* __restrict__ edata,
    const int* __restrict__ off, float* __restrict__ out, int cap, int R) {
    int g = blockIdx.x * blockDim.x + threadIdx.x;
    if (g >= cap) return;

    int r = 0;
    for (int rr = 1; rr < R; rr++) r += (g >= off[rr]) ? 1 : 0;
    r = __builtin_amdgcn_readfirstlane(r);

    int4 rec = edata[g];               // coalesced 16 B/lane
    bool valid = (rec.z >= 0);
    int sn = valid ? rec.x : 0;
    int dn = valid ? rec.y : 0;

    // rows are 64 B of f16: 4 x 16B loads each
    const uint4* As = (const uint4*)(Ah + (size_t)sn * KDIM);
    const uint4* Ad = (const uint4*)(Ah + (size_t)dn * KDIM);
    unsigned int sp[16], dp[16];
#pragma unroll
    for (int q = 0; q < 4; q++) {
        uint4 s4 = As[q];
        uint4 d4 = Ad[q];
        sp[4 * q + 0] = s4.x; sp[4 * q + 1] = s4.y;
        sp[4 * q + 2] = s4.z; sp[4 * q + 3] = s4.w;
        dp[4 * q + 0] = d4.x; dp[4 * q + 1] = d4.y;
        dp[4 * q + 2] = d4.z; dp[4 * q + 3] = d4.w;
    }

    // W row i = 32 f16 = 16 dwords: wave-uniform -> s_load, SGPR operand to dot2
    const unsigned int* __restrict__ Wr =
        (const unsigned int*)(Wh + (size_t)r * (KDIM * KDIM));
    float total = 0.0f;
#pragma unroll
    for (int i = 0; i < KDIM; i++) {
        float acc = 0.0f;
#pragma unroll
        for (int j2 = 0; j2 < KDIM / 2; j2++) {
            half2v w = __builtin_bit_cast(half2v, Wr[i * 16 + j2]);
            half2v d = __builtin_bit_cast(half2v, dp[j2]);
#if __has_builtin(__builtin_amdgcn_fdot2)
            acc = __builtin_amdgcn_fdot2(w, d, acc, false);
#else
            acc = fmaf((float)w[0], (float)d[0], acc);
            acc = fmaf((float)w[1], (float)d[1], acc);
#endif
        }
        half2v s2 = __builtin_bit_cast(half2v, sp[i >> 1]);
        float sv = (float)s2[i & 1];
        total = fmaf(sv, acc, total);
    }

    if (valid) out[rec.z] = total + bias[r];
}

// ---- fallback (no workspace): fp32, W staged in LDS, per-lane relation ----
__global__ __launch_bounds__(256) void gather_unsorted_kernel(
    const float* __restrict__ A, const int* __restrict__ ei,
    const int* __restrict__ et,
    const float* __restrict__ logits, const float* __restrict__ la,
    const float* __restrict__ bias, float* __restrict__ out, int E, int R) {
    __shared__ float Wl[RMAX * 1032];
    int total_w = R * KDIM * KDIM;
    for (int t = threadIdx.x; t < total_w; t += blockDim.x) {
        int r = t / (KDIM * KDIM);
        int ij = t % (KDIM * KDIM);
        Wl[r * 1032 + ij] = gate_weight_(logits[t], la[t]);
    }
    __syncthreads();

    for (int e = blockIdx.x * blockDim.x + threadIdx.x; e < E;
         e += gridDim.x * blockDim.x) {
        int r = et[e];
        int sn = ei[e];
        int dn = ei[E + e];
        const float4* As = (const float4*)(A + (size_t)sn * KDIM);
        const float4* Ad = (const float4*)(A + (size_t)dn * KDIM);
        float sv[KDIM], dv[KDIM];
#pragma unroll
        for (int q = 0; q < KDIM / 4; q++) {
            float4 s4 = As[q];
            float4 d4 = Ad[q];
            sv[4 * q + 0] = s4.x; sv[4 * q + 1] = s4.y;
            sv[4 * q + 2] = s4.z; sv[4 * q + 3] = s4.w;
            dv[4 * q + 0] = d4.x; dv[4 * q + 1] = d4.y;
            dv[4 * q + 2] = d4.z; dv[4 * q + 3] = d4.w;
        }
        float totalv = 0.0f;
#pragma unroll
        for (int i = 0; i < KDIM; i++) {
            const float* Wrow = &Wl[r * 1032 + i * KDIM];
            float acc = 0.0f;
#pragma unroll
            for (int j = 0; j < KDIM / 4; j++) {
                float4 w4 = ((const float4*)Wrow)[j];
                acc = fmaf(w4.x, dv[4 * j + 0], acc);
                acc = fmaf(w4.y, dv[4 * j + 1], acc);
                acc = fmaf(w4.z, dv[4 * j + 2], acc);
                acc = fmaf(w4.w, dv[4 * j + 3], acc);
            }
            totalv = fmaf(sv[i], acc, totalv);
        }
        out[e] = totalv + bias[r];
    }
}

extern "C" void kernel_launch(void* const* d_in, const int* in_sizes, int n_in,
                              void* d_out, int out_size, void* d_ws, size_t ws_size,
                              hipStream_t stream) {
    const float* A      = (const float*)d_in[0];   // [N, 32]
    const int*   ei     = (const int*)d_in[1];     // [2, E]
    const int*   et     = (const int*)d_in[2];     // [E]
    const float* logits = (const float*)d_in[3];   // [R, 32, 32]
    const float* la     = (const float*)d_in[4];   // [R, 32, 32]
    const float* bias   = (const float*)d_in[5];   // [R]
    float* out = (float*)d_out;

    int E = in_sizes[2];
    int R = in_sizes[5];
    int n = in_sizes[3];   // R*K*K
    int nA = in_sizes[0];  // nodes * K

    int cap = E + 64 * RMAX;
    size_t ahb = ((size_t)nA * 2 + 15) & ~(size_t)15;
    // ws layout: Wh (16384) | off (64) | bh (8192) | Ah (ahb) | edata (cap*16)
    size_t edata_off = 16384 + 64 + (size_t)NBLK * RMAX * 4 + ahb;
    size_t need = edata_off + (size_t)cap * 16;

    if (R <= RMAX && ws_size >= need) {
        char* ws = (char*)d_ws;
        _Float16* Wh = (_Float16*)(ws);
        int* off     = (int*)(ws + 16384);
        int* bh      = (int*)(ws + 16384 + 64);
        _Float16* Ah = (_Float16*)(ws + 16384 + 64 + NBLK * RMAX * 4);
        int4* edata  = (int4*)(ws + edata_off);

        int chunk = (E + NBLK - 1) / NBLK;

        prep_kernel<<<NBLK, 256, 0, stream>>>(
            et, E, chunk, bh, R, logits, la, Wh, n, A, Ah, nA);
        scan2_kernel<<<1, 512, 0, stream>>>(bh, off, edata, R);
        scatter3_kernel<<<NBLK, 256, 0, stream>>>(et, ei, E, chunk, bh, edata, R);
        gather3_kernel<<<(cap + 255) / 256, 256, 0, stream>>>(
            Ah, Wh, bias, edata, off, out, cap, R);
    } else {
        int gblocks = (E + 255) / 256;
        if (gblocks > 2048) gblocks = 2048;
        gather_unsorted_kernel<<<gblocks, 256, 0, stream>>>(
            A, ei, et, logits, la, bias, out, E, R);
    }
}

// Round 9
// 105.978 us; speedup vs baseline: 7.8762x; 1.0203x over previous
//
#include <hip/hip_runtime.h>
#include <hip/hip_bf16.h>
#include <cstdint>

#define KDIM 32
#define RMAX 8
#define NBLK 256   // blocks for hist/scatter passes

typedef _Float16 half2v __attribute__((ext_vector_type(2)));
typedef _Float16 half4v __attribute__((ext_vector_type(4)));
typedef float    f32x4  __attribute__((ext_vector_type(4)));

#if __has_builtin(__builtin_amdgcn_mfma_f32_16x16x16f16)
#define USE_MFMA 1
#else
#define USE_MFMA 0
#endif

__device__ __forceinline__ float sigmoidf_(float x) {
    return 1.0f / (1.0f + expf(-x));
}

__device__ __forceinline__ float gate_weight_(float logit, float log_alpha) {
    // hard-concrete eval gate: pre = clip(la/temp, -2, 2); z = sig(pre)*1.2-0.1; clip[0,1]
    float pre = log_alpha * 1.5f;                 // / (2/3)
    pre = fminf(fmaxf(pre, -2.0f), 2.0f);
    float z = sigmoidf_(pre) * 1.2f - 0.1f;
    z = fminf(fmaxf(z, 0.0f), 1.0f);
    return sigmoidf_(logit) * z;
}

// ---- kernel 1: per-block histogram + W->f16 + A->f16 conversion ----
__global__ __launch_bounds__(256) void prep_kernel(
    const int* __restrict__ et, int E, int chunk,
    int* __restrict__ bh /* [NBLK][RMAX] */, int R,
    const float* __restrict__ logits, const float* __restrict__ la,
    _Float16* __restrict__ Wh, int n,
    const float* __restrict__ A, _Float16* __restrict__ Ah, int nA) {
    int g = blockIdx.x * blockDim.x + threadIdx.x;
    // fused gate weights -> f16 (n = R*K*K = 8192 << grid)
    if (g < n) Wh[g] = (_Float16)gate_weight_(logits[g], la[g]);

    // A fp32 -> f16 table, coalesced grid-stride over float4 groups
    int nthreads = gridDim.x * blockDim.x;
    int n4 = nA >> 2;
    for (int i4 = g; i4 < n4; i4 += nthreads) {
        float4 v = ((const float4*)A)[i4];
        half2v h0; h0[0] = (_Float16)v.x; h0[1] = (_Float16)v.y;
        half2v h1; h1[0] = (_Float16)v.z; h1[1] = (_Float16)v.w;
        ((half2v*)Ah)[i4 * 2 + 0] = h0;
        ((half2v*)Ah)[i4 * 2 + 1] = h1;
    }

    __shared__ int h[RMAX];
    if ((int)threadIdx.x < RMAX) h[threadIdx.x] = 0;
    __syncthreads();
    int b = blockIdx.x;
    int start = b * chunk;
    int end = start + chunk;
    if (end > E) end = E;
    for (int i = start + threadIdx.x; i < end; i += blockDim.x) {
        atomicAdd(&h[et[i]], 1);
    }
    __syncthreads();
    if ((int)threadIdx.x < RMAX) bh[b * RMAX + threadIdx.x] = h[threadIdx.x];
}

// ---- kernel 2: PARALLEL scan (1 block, 512 threads = 8 waves) ----
__global__ __launch_bounds__(512) void scan2_kernel(
    int* __restrict__ bh, int* __restrict__ off,
    int4* __restrict__ edata, int R) {
    __shared__ int tr[RMAX][NBLK];     // transposed histograms, 8 KB
    __shared__ int cnt_s[RMAX];
    __shared__ int off_s[RMAX + 1];
    int t = threadIdx.x;

    for (int i = t; i < NBLK * RMAX; i += 512) {
        int b = i / RMAX, r = i % RMAX;
        tr[r][b] = bh[i];
    }
    __syncthreads();

    int w = t >> 6;        // wave id = relation
    int lane = t & 63;
    if (w < R) {
        int b0 = lane * 4;
        int v0 = tr[w][b0 + 0];
        int v1 = tr[w][b0 + 1];
        int v2 = tr[w][b0 + 2];
        int v3 = tr[w][b0 + 3];
        int s0 = v0, s1 = s0 + v1, s2 = s1 + v2, s3 = s2 + v3;
        int lanesum = s3;
        int sc = lanesum;
#pragma unroll
        for (int d = 1; d < 64; d <<= 1) {
            int up = __shfl_up(sc, d, 64);
            if (lane >= d) sc += up;
        }
        int excl = sc - lanesum;
        tr[w][b0 + 0] = excl;
        tr[w][b0 + 1] = excl + s0;
        tr[w][b0 + 2] = excl + s1;
        tr[w][b0 + 3] = excl + s2;
        if (lane == 63) cnt_s[w] = sc;
    }
    __syncthreads();

    if (t == 0) {
        int o = 0;
        off_s[0] = 0;
        for (int r = 0; r < R; r++) {
            o += (cnt_s[r] + 63) & ~63;
            off_s[r + 1] = o;
        }
        for (int r = 0; r <= R; r++) off[r] = off_s[r];
    }
    __syncthreads();

    for (int i = t; i < NBLK * RMAX; i += 512) {
        int b = i / RMAX, r = i % RMAX;
        bh[i] = tr[r][b] + ((r < R) ? off_s[r] : 0);
    }
    for (int r = 0; r < R; r++) {
        int padStart = off_s[r] + cnt_s[r];
        int padEnd = off_s[r + 1];
        for (int i = padStart + t; i < padEnd; i += 512) {
            edata[i] = make_int4(0, 0, -1, 0);
        }
    }
}

// ---- kernel 3: scatter packed records {src, dst, e} via per-block LDS cursors ----
__global__ __launch_bounds__(256) void scatter3_kernel(
    const int* __restrict__ et, const int* __restrict__ ei, int E, int chunk,
    const int* __restrict__ bh, int4* __restrict__ edata, int R) {
    __shared__ int cur[RMAX];
    int b = blockIdx.x;
    if ((int)threadIdx.x < RMAX) cur[threadIdx.x] = bh[b * RMAX + threadIdx.x];
    __syncthreads();
    int start = b * chunk;
    int end = start + chunk;
    if (end > E) end = E;
    for (int i = start + threadIdx.x; i < end; i += blockDim.x) {
        int r = et[i];
        int sn = ei[i];
        int dn = ei[E + i];
        int pos = atomicAdd(&cur[r], 1);
        edata[pos] = make_int4(sn, dn, i, 0);
    }
}

#if USE_MFMA
// ---- kernel 4 (MFMA): wave processes 64 slots as 4 groups of 16 edges.
// Per group: Z = W (32x32) x D^T (32x16) via 4 mfma_16x16x16_f16;
// C = S (16x32) x Z (32x16) via 2 more; diag(C) = logits.
// Layouts (AMD matrix-core mapping, C-layout m89-verified):
//   A: lane l reg i = A[l%16][(l/16)*4+i]
//   B: lane l reg i = B[(l/16)*4+i][l%16]
//   C: lane l reg q = C[(l/16)*4+q][l%16]
// C-layout == B-layout (row-group structure identical) -> Z feeds M3 in-place.
__global__ __launch_bounds__(256) void gather4_kernel(
    const _Float16* __restrict__ Ah, const _Float16* __restrict__ Wh,
    const float* __restrict__ bias, const int4* __restrict__ edata,
    const int* __restrict__ off, float* __restrict__ out, int capA, int R) {
    int g = blockIdx.x * blockDim.x + threadIdx.x;
    int lane = threadIdx.x & 63;
    int lm = lane & 15;          // edge slot within group / matrix col
    int lg = lane >> 4;          // k/row group
    int kq = lg * 4;

    // bucket (relation) of this wave; off[] entries are 64-aligned -> uniform
    int r = 0;
    for (int rr = 1; rr < R; rr++) r += (g >= off[rr]) ? 1 : 0;
    r = __builtin_amdgcn_readfirstlane(r);
    float br = bias[r];

    // W fragments, loaded once per wave (A-layout, rows 0-15 and 16-31, k-halves)
    const _Float16* Wr = Wh + (size_t)r * (KDIM * KDIM);
    half4v aw1 = *(const half4v*)(Wr + lm * KDIM + kq);
    half4v aw2 = *(const half4v*)(Wr + lm * KDIM + 16 + kq);
    half4v aw3 = *(const half4v*)(Wr + (16 + lm) * KDIM + kq);
    half4v aw4 = *(const half4v*)(Wr + (16 + lm) * KDIM + 16 + kq);

    int wbase = (blockIdx.x * blockDim.x + (threadIdx.x & ~63));
    f32x4 zeroF = {0.0f, 0.0f, 0.0f, 0.0f};
    bool diag_lane = (lg == (lm >> 2));

#pragma unroll
    for (int s = 0; s < 4; s++) {
        int4 rec = edata[wbase + s * 16 + lm];   // 4 lanes share each record (L1 bcast)
        bool valid = (rec.z >= 0);
        int sn = valid ? rec.x : 0;
        int dn = valid ? rec.y : 0;

        const _Float16* Sp = Ah + (size_t)sn * KDIM;
        const _Float16* Dp = Ah + (size_t)dn * KDIM;
        half4v as1 = *(const half4v*)(Sp + kq);        // S A-frag k 0-15
        half4v as2 = *(const half4v*)(Sp + 16 + kq);   // k 16-31
        half4v bd1 = *(const half4v*)(Dp + kq);        // D^T B-frag k 0-15
        half4v bd2 = *(const half4v*)(Dp + 16 + kq);   // k 16-31

        // Z = W x D^T  (rows 0-15 -> z1, rows 16-31 -> z2)
        f32x4 z1 = __builtin_amdgcn_mfma_f32_16x16x16f16(aw1, bd1, zeroF, 0, 0, 0);
        z1 = __builtin_amdgcn_mfma_f32_16x16x16f16(aw2, bd2, z1, 0, 0, 0);
        f32x4 z2 = __builtin_amdgcn_mfma_f32_16x16x16f16(aw3, bd1, zeroF, 0, 0, 0);
        z2 = __builtin_amdgcn_mfma_f32_16x16x16f16(aw4, bd2, z2, 0, 0, 0);

        // f32 C-layout -> f16 B-operand (identical lane mapping, just convert)
        half4v zb1, zb2;
#if __has_builtin(__builtin_amdgcn_cvt_pkrtz)
        half2v t0 = __builtin_bit_cast(half2v, __builtin_amdgcn_cvt_pkrtz(z1[0], z1[1]));
        half2v t1 = __builtin_bit_cast(half2v, __builtin_amdgcn_cvt_pkrtz(z1[2], z1[3]));
        half2v t2 = __builtin_bit_cast(half2v, __builtin_amdgcn_cvt_pkrtz(z2[0], z2[1]));
        half2v t3 = __builtin_bit_cast(half2v, __builtin_amdgcn_cvt_pkrtz(z2[2], z2[3]));
        zb1[0] = t0[0]; zb1[1] = t0[1]; zb1[2] = t1[0]; zb1[3] = t1[1];
        zb2[0] = t2[0]; zb2[1] = t2[1]; zb2[2] = t3[0]; zb2[3] = t3[1];
#else
        zb1[0] = (_Float16)z1[0]; zb1[1] = (_Float16)z1[1];
        zb1[2] = (_Float16)z1[2]; zb1[3] = (_Float16)z1[3];
        zb2[0] = (_Float16)z2[0]; zb2[1] = (_Float16)z2[1];
        zb2[2] = (_Float16)z2[2]; zb2[3] = (_Float16)z2[3];
#endif

        // C = S x Z ; diagonal = logits
        f32x4 c = __builtin_amdgcn_mfma_f32_16x16x16f16(as1, zb1, zeroF, 0, 0, 0);
        c = __builtin_amdgcn_mfma_f32_16x16x16f16(as2, zb2, c, 0, 0, 0);

        if (valid && diag_lane) out[rec.z] = c[lm & 3] + br;
    }
}
#else
// ---- kernel 4 (fallback): f16 fdot2, one edge per lane ----
__global__ __launch_bounds__(256) void gather4_kernel(
    const _Float16* __restrict__ Ah, const _Float16* __restrict__ Wh,
    const float* __restrict__ bias, const int4* __restrict__ edata,
    const int* __restrict__ off, float* __restrict__ out, int capA, int R) {
    int g = blockIdx.x * blockDim.x + threadIdx.x;
    if (g >= capA) return;

    int r = 0;
    for (int rr = 1; rr < R; rr++) r += (g >= off[rr]) ? 1 : 0;
    r = __builtin_amdgcn_readfirstlane(r);

    int4 rec = edata[g];
    bool valid = (rec.z >= 0);
    int sn = valid ? rec.x : 0;
    int dn = valid ? rec.y : 0;

    const uint4* As = (const uint4*)(Ah + (size_t)sn * KDIM);
    const uint4* Ad = (const uint4*)(Ah + (size_t)dn * KDIM);
    unsigned int sp[16], dp[16];
#pragma unroll
    for (int q = 0; q < 4; q++) {
        uint4 s4 = As[q];
        uint4 d4 = Ad[q];
        sp[4 * q + 0] = s4.x; sp[4 * q + 1] = s4.y;
        sp[4 * q + 2] = s4.z; sp[4 * q + 3] = s4.w;
        dp[4 * q + 0] = d4.x; dp[4 * q + 1] = d4.y;
        dp[4 * q + 2] = d4.z; dp[4 * q + 3] = d4.w;
    }

    const unsigned int* __restrict__ Wr =
        (const unsigned int*)(Wh + (size_t)r * (KDIM * KDIM));
    float total = 0.0f;
#pragma unroll
    for (int i = 0; i < KDIM; i++) {
        float acc = 0.0f;
#pragma unroll
        for (int j2 = 0; j2 < KDIM / 2; j2++) {
            half2v w = __builtin_bit_cast(half2v, Wr[i * 16 + j2]);
            half2v d = __builtin_bit_cast(half2v, dp[j2]);
#if __has_builtin(__builtin_amdgcn_fdot2)
            acc = __builtin_amdgcn_fdot2(w, d, acc, false);
#else
            acc = fmaf((float)w[0], (float)d[0], acc);
            acc = fmaf((float)w[1], (float)d[1], acc);
#endif
        }
        half2v s2 = __builtin_bit_cast(half2v, sp[i >> 1]);
        float sv = (float)s2[i & 1];
        total = fmaf(sv, acc, total);
    }

    if (valid) out[rec.z] = total + bias[r];
}
#endif

// ---- fallback (no workspace): fp32, W staged in LDS, per-lane relation ----
__global__ __launch_bounds__(256) void gather_unsorted_kernel(
    const float* __restrict__ A, const int* __restrict__ ei,
    const int* __restrict__ et,
    const float* __restrict__ logits, const float* __restrict__ la,
    const float* __restrict__ bias, float* __restrict__ out, int E, int R) {
    __shared__ float Wl[RMAX * 1032];
    int total_w = R * KDIM * KDIM;
    for (int t = threadIdx.x; t < total_w; t += blockDim.x) {
        int r = t / (KDIM * KDIM);
        int ij = t % (KDIM * KDIM);
        Wl[r * 1032 + ij] = gate_weight_(logits[t], la[t]);
    }
    __syncthreads();

    for (int e = blockIdx.x * blockDim.x + threadIdx.x; e < E;
         e += gridDim.x * blockDim.x) {
        int r = et[e];
        int sn = ei[e];
        int dn = ei[E + e];
        const float4* As = (const float4*)(A + (size_t)sn * KDIM);
        const float4* Ad = (const float4*)(A + (size_t)dn * KDIM);
        float sv[KDIM], dv[KDIM];
#pragma unroll
        for (int q = 0; q < KDIM / 4; q++) {
            float4 s4 = As[q];
            float4 d4 = Ad[q];
            sv[4 * q + 0] = s4.x; sv[4 * q + 1] = s4.y;
            sv[4 * q + 2] = s4.z; sv[4 * q + 3] = s4.w;
            dv[4 * q + 0] = d4.x; dv[4 * q + 1] = d4.y;
            dv[4 * q + 2] = d4.z; dv[4 * q + 3] = d4.w;
        }
        float totalv = 0.0f;
#pragma unroll
        for (int i = 0; i < KDIM; i++) {
            const float* Wrow = &Wl[r * 1032 + i * KDIM];
            float acc = 0.0f;
#pragma unroll
            for (int j = 0; j < KDIM / 4; j++) {
                float4 w4 = ((const float4*)Wrow)[j];
                acc = fmaf(w4.x, dv[4 * j + 0], acc);
                acc = fmaf(w4.y, dv[4 * j + 1], acc);
                acc = fmaf(w4.z, dv[4 * j + 2], acc);
                acc = fmaf(w4.w, dv[4 * j + 3], acc);
            }
            totalv = fmaf(sv[i], acc, totalv);
        }
        out[e] = totalv + bias[r];
    }
}

extern "C" void kernel_launch(void* const* d_in, const int* in_sizes, int n_in,
                              void* d_out, int out_size, void* d_ws, size_t ws_size,
                              hipStream_t stream) {
    const float* A      = (const float*)d_in[0];   // [N, 32]
    const int*   ei     = (const int*)d_in[1];     // [2, E]
    const int*   et     = (const int*)d_in[2];     // [E]
    const float* logits = (const float*)d_in[3];   // [R, 32, 32]
    const float* la     = (const float*)d_in[4];   // [R, 32, 32]
    const float* bias   = (const float*)d_in[5];   // [R]
    float* out = (float*)d_out;

    int E = in_sizes[2];
    int R = in_sizes[5];
    int n = in_sizes[3];   // R*K*K
    int nA = in_sizes[0];  // nodes * K

    // capA: slot capacity rounded to 256 so whole blocks stay in-bounds;
    // slots beyond off[R] are 0xAA poison -> rec.z < 0 -> treated invalid.
    int capA = (E + 64 * RMAX + 255) & ~255;
    size_t ahb = ((size_t)nA * 2 + 15) & ~(size_t)15;
    // ws layout: Wh (16384) | off (64) | bh (8192) | Ah (ahb) | edata (capA*16)
    size_t edata_off = 16384 + 64 + (size_t)NBLK * RMAX * 4 + ahb;
    size_t need = edata_off + (size_t)capA * 16;

    if (R <= RMAX && ws_size >= need) {
        char* ws = (char*)d_ws;
        _Float16* Wh = (_Float16*)(ws);
        int* off     = (int*)(ws + 16384);
        int* bh      = (int*)(ws + 16384 + 64);
        _Float16* Ah = (_Float16*)(ws + 16384 + 64 + NBLK * RMAX * 4);
        int4* edata  = (int4*)(ws + edata_off);

        int chunk = (E + NBLK - 1) / NBLK;

        prep_kernel<<<NBLK, 256, 0, stream>>>(
            et, E, chunk, bh, R, logits, la, Wh, n, A, Ah, nA);
        scan2_kernel<<<1, 512, 0, stream>>>(bh, off, edata, R);
        scatter3_kernel<<<NBLK, 256, 0, stream>>>(et, ei, E, chunk, bh, edata, R);
        gather4_kernel<<<capA / 256, 256, 0, stream>>>(
            Ah, Wh, bias, edata, off, out, capA, R);
    } else {
        int gblocks = (E + 255) / 256;
        if (gblocks > 2048) gblocks = 2048;
        gather_unsorted_kernel<<<gblocks, 256, 0, stream>>>(
            A, ei, et, logits, la, bias, out, E, R);
    }
}